// Round 5
// baseline (301.208 us; speedup 1.0000x reference)
//
#include <hip/hip_runtime.h>

typedef __attribute__((ext_vector_type(8))) short short8;
typedef __attribute__((ext_vector_type(4))) short s16x4;
typedef __attribute__((ext_vector_type(4))) float f32x4;
typedef __attribute__((ext_vector_type(4))) int int4v;
typedef __attribute__((ext_vector_type(2))) unsigned int uint2v;
typedef __attribute__((ext_vector_type(4))) unsigned int uint4v;

#define MFMA16x16x32(a, b, c) __builtin_amdgcn_mfma_f32_16x16x32_bf16((a), (b), (c), 0, 0, 0)

// (1/sqrt(64)) * log2(e): folded into the Q projection epilogue, so the
// attention softmax is x = exp2(st) with st = dot(q_scaled,k) + {0,-96}.
#define QK_SCALE 0.18033688011112042f

__device__ __forceinline__ unsigned short f2bf(float f) {
  unsigned u = __builtin_bit_cast(unsigned, f);
  u += 0x7fffu + ((u >> 16) & 1u);  // RNE
  return (unsigned short)(u >> 16);
}

__device__ __forceinline__ unsigned cvt_pk(float lo, float hi) {
  unsigned r;
  asm("v_cvt_pk_bf16_f32 %0, %1, %2" : "=v"(r) : "v"(lo), "v"(hi));
  return r;
}

// PV matmul: K=16 bf16 MFMA whose A-fragment (row=lane&15, k=(lane>>4)*4+j)
// exactly matches the in-register P layout produced by swapped QK^T.
__device__ __forceinline__ f32x4 mfma16(s16x4 a, s16x4 b, f32x4 c) {
  f32x4 d;
  asm("v_mfma_f32_16x16x16_bf16 %0, %1, %2, %3" : "=v"(d) : "v"(a), "v"(b), "v"(c));
  return d;
}

// fp32 -> bf16 bulk convert, 8 elems/thread
__global__ __launch_bounds__(256) void prep_bf16(const float* __restrict__ in,
                                                 unsigned short* __restrict__ out) {
  const int i = (blockIdx.x * 256 + threadIdx.x) * 8;
  f32x4 a = *(const f32x4*)(in + i);
  f32x4 b = *(const f32x4*)(in + i + 4);
  uint4v r;
  r[0] = cvt_pk(a[0], a[1]);
  r[1] = cvt_pk(a[2], a[3]);
  r[2] = cvt_pk(b[0], b[1]);
  r[3] = cvt_pk(b[2], b[3]);
  *(uint4v*)(out + i) = r;
}

// mask int32 -> f32 additive bias (0 or -96, log2 domain), 8 elems/thread
__global__ __launch_bounds__(256) void prep_biasf(const int* __restrict__ mask,
                                                  float* __restrict__ bias) {
  const int i = (blockIdx.x * 256 + threadIdx.x) * 8;
  int4v m0 = *(const int4v*)(mask + i);
  int4v m1 = *(const int4v*)(mask + i + 4);
  f32x4 o0, o1;
#pragma unroll
  for (int j = 0; j < 4; ++j) o0[j] = (m0[j] == 0) ? -96.0f : 0.0f;
#pragma unroll
  for (int j = 0; j < 4; ++j) o1[j] = (m1[j] == 0) ? -96.0f : 0.0f;
  *(f32x4*)(bias + i) = o0;
  *(f32x4*)(bias + i + 4) = o1;
}

// C[M,N] = (A[M,K] @ B[N,K]^T + bias) * scl; A,B bf16; fp32 accum.
// EPI 0: bf16 out, [B,H,S,D] layout (m=b*2048+s, n=h*64+d), bias[n]  (Q/K proj)
// EPI 1: bf16 out, [B,H,D,S] layout (m=h*64+d, n=b*2048+s), bias[m]  (V proj, swapped)
// EPI 2: f32 out, plain row-major [M,N], bias[n]                     (final proj)
template <int EPI>
__global__ __launch_bounds__(256) void gemm_bt(
    const unsigned short* __restrict__ A, const unsigned short* __restrict__ B,
    const float* __restrict__ bias, void* __restrict__ out,
    int M, int N, int K, float scl) {
  __shared__ unsigned short Asm[128][72];
  __shared__ unsigned short Bsm[128][72];
  const int tid = threadIdx.x;
  const int lane = tid & 63;
  const int wid = tid >> 6;
  const int wr = wid >> 1, wc = wid & 1;
  const int mbase = blockIdx.y * 128, nbase = blockIdx.x * 128;

  f32x4 acc[4][4] = {};

  for (int k0 = 0; k0 < K; k0 += 64) {
#pragma unroll
    for (int r = 0; r < 4; ++r) {
      const int c = tid + 256 * r;
      const int row = c >> 3, col = (c & 7) << 3;
      *(short8*)&Asm[row][col] = *(const short8*)(A + (size_t)(mbase + row) * K + k0 + col);
      *(short8*)&Bsm[row][col] = *(const short8*)(B + (size_t)(nbase + row) * K + k0 + col);
    }
    __syncthreads();
#pragma unroll
    for (int ks = 0; ks < 2; ++ks) {
      const int kk = ks * 32 + (lane >> 4) * 8;
      short8 af[4], bfv[4];
#pragma unroll
      for (int t = 0; t < 4; ++t) {
        af[t] = *(const short8*)&Asm[wr * 64 + t * 16 + (lane & 15)][kk];
        bfv[t] = *(const short8*)&Bsm[wc * 64 + t * 16 + (lane & 15)][kk];
      }
#pragma unroll
      for (int tm = 0; tm < 4; ++tm)
#pragma unroll
        for (int tn = 0; tn < 4; ++tn)
          acc[tm][tn] = MFMA16x16x32(af[tm], bfv[tn], acc[tm][tn]);
    }
    __syncthreads();
  }

  float bn[4];
  if (EPI == 0 || EPI == 2) {
#pragma unroll
    for (int tn = 0; tn < 4; ++tn)
      bn[tn] = bias[nbase + wc * 64 + tn * 16 + (lane & 15)];
  }
  float bm[4][4];
  if (EPI == 1) {
#pragma unroll
    for (int tm = 0; tm < 4; ++tm)
#pragma unroll
      for (int i = 0; i < 4; ++i)
        bm[tm][i] = bias[mbase + wr * 64 + tm * 16 + (lane >> 4) * 4 + i];
  }
#pragma unroll
  for (int tm = 0; tm < 4; ++tm) {
#pragma unroll
    for (int i = 0; i < 4; ++i) {
      const int m = mbase + wr * 64 + tm * 16 + (lane >> 4) * 4 + i;
#pragma unroll
      for (int tn = 0; tn < 4; ++tn) {
        const int n = nbase + wc * 64 + tn * 16 + (lane & 15);
        const float v = (acc[tm][tn][i] + (EPI == 1 ? bm[tm][i] : bn[tn])) * scl;
        if (EPI == 0) {
          const size_t idx =
              (((size_t)(m >> 11) * 16 + (n >> 6)) * 2048 + (m & 2047)) * 64 + (n & 63);
          ((unsigned short*)out)[idx] = f2bf(v);
        } else if (EPI == 1) {
          const size_t idx =
              (((size_t)(n >> 11) * 16 + (m >> 6)) * 64 + (m & 63)) * 2048 + (n & 2047);
          ((unsigned short*)out)[idx] = f2bf(v);
        } else {
          ((float*)out)[(size_t)m * N + n] = v;
        }
      }
    }
  }
}

// Flash attention, fixed-reference softmax. 256 threads = 4 waves, 128 q-rows
// per block, KV tiles of 64. Swapped S^T = K@Q^T (Q pre-scaled); mask bias
// enters as the MFMA C-initializer (f32 0/-96); softmax = one v_exp_f32 per
// score; P stays in registers and feeds PV via 16x16x16 MFMA. XCD-swizzled.
__global__ __launch_bounds__(256, 4) void attn_fused(
    const unsigned short* __restrict__ Qh, const unsigned short* __restrict__ Kh,
    const unsigned short* __restrict__ VT, const float* __restrict__ Biasf,
    unsigned short* __restrict__ Ob) {
  __shared__ unsigned short Kl[64][72];
  __shared__ unsigned short Vl[64][72];  // VT tile: row = d, col = kv
  const int tid = threadIdx.x, lane = tid & 63, w = tid >> 6;
  const int m = lane & 15, g = lane >> 4;
  // XCD swizzle: all 16 q-tiles of 8 consecutive bh-groups land on one XCD.
  const int wg = ((blockIdx.x & 7) << 7) + (blockIdx.x >> 3);
  const int qt = wg & 15, bh = wg >> 4;
  const int q0 = qt << 7;
  const unsigned short* Qb = Qh + (size_t)bh * (2048 * 64);
  const unsigned short* Kb = Kh + (size_t)bh * (2048 * 64);
  const unsigned short* Vb = VT + (size_t)bh * (64 * 2048);

  short8 qf[2][2];
#pragma unroll
  for (int ks = 0; ks < 2; ++ks)
#pragma unroll
    for (int tq = 0; tq < 2; ++tq)
      qf[ks][tq] = *(const short8*)(Qb +
          (size_t)(q0 + w * 32 + tq * 16 + m) * 64 + ks * 32 + g * 8);

  const float* brow[2];
#pragma unroll
  for (int tq = 0; tq < 2; ++tq)
    brow[tq] = Biasf + (size_t)(q0 + w * 32 + tq * 16 + m) * 2048 + g * 4;

  f32x4 acc[2][4] = {};
  float l_run[2] = {0.f, 0.f};

  for (int kt = 0; kt < 32; ++kt) {
    const int kv0 = kt << 6;
    __syncthreads();  // prior-iter Kl/Vl reads done
#pragma unroll
    for (int r = 0; r < 2; ++r) {
      const int c = tid + 256 * r;
      const int row = c >> 3, col = (c & 7) << 3;
      *(short8*)&Kl[row][col] = *(const short8*)(Kb + (size_t)(kv0 + row) * 64 + col);
      *(short8*)&Vl[row][col] = *(const short8*)(Vb + (size_t)row * 2048 + kv0 + col);
    }
    // bias loads for this tile (drained by the same barrier as staging)
    f32x4 bini[2][4];
#pragma unroll
    for (int tq = 0; tq < 2; ++tq)
#pragma unroll
      for (int tkv = 0; tkv < 4; ++tkv)
        bini[tq][tkv] = *(const f32x4*)(brow[tq] + kv0 + tkv * 16);
    __syncthreads();

    // S^T = K @ Q^T + bias-init : rows = kv (64), cols = q (this wave's 32)
    f32x4 st[4][2];
#pragma unroll
    for (int tkv = 0; tkv < 4; ++tkv)
#pragma unroll
      for (int tq = 0; tq < 2; ++tq) st[tkv][tq] = bini[tq][tkv];
    __builtin_amdgcn_s_setprio(1);
#pragma unroll
    for (int ks = 0; ks < 2; ++ks) {
      const int kk = ks * 32 + g * 8;
      short8 kf[4];
#pragma unroll
      for (int t = 0; t < 4; ++t) kf[t] = *(const short8*)&Kl[t * 16 + m][kk];
#pragma unroll
      for (int tkv = 0; tkv < 4; ++tkv)
#pragma unroll
        for (int tq = 0; tq < 2; ++tq)
          st[tkv][tq] = MFMA16x16x32(kf[tkv], qf[ks][tq], st[tkv][tq]);
    }
    __builtin_amdgcn_s_setprio(0);

    // softmax: one exp2 per score; P packed to bf16 pairs, stays in registers
    uint2v pa[2][4];
#pragma unroll
    for (int tq = 0; tq < 2; ++tq) {
      float rsum = l_run[tq];
#pragma unroll
      for (int tkv = 0; tkv < 4; ++tkv) {
        const float x0 = __builtin_amdgcn_exp2f(st[tkv][tq][0]);
        const float x1 = __builtin_amdgcn_exp2f(st[tkv][tq][1]);
        const float x2 = __builtin_amdgcn_exp2f(st[tkv][tq][2]);
        const float x3 = __builtin_amdgcn_exp2f(st[tkv][tq][3]);
        rsum += (x0 + x1) + (x2 + x3);
        pa[tq][tkv][0] = cvt_pk(x0, x1);
        pa[tq][tkv][1] = cvt_pk(x2, x3);
      }
      l_run[tq] = rsum;
    }

    // O += P @ V via 16x16x16 MFMA; P fragments already in registers.
    asm volatile("s_nop 1");  // VALU(cvt_pk) -> MFMA SrcA hazard guard
    __builtin_amdgcn_s_setprio(1);
#pragma unroll
    for (int tn = 0; tn < 4; ++tn) {
      s16x4 vf[4];
#pragma unroll
      for (int tkv = 0; tkv < 4; ++tkv)
        vf[tkv] = *(const s16x4*)&Vl[tn * 16 + m][tkv * 16 + g * 4];
#pragma unroll
      for (int tm = 0; tm < 2; ++tm)
#pragma unroll
        for (int tkv = 0; tkv < 4; ++tkv)
          acc[tm][tn] = mfma16(__builtin_bit_cast(s16x4, pa[tm][tkv]), vf[tkv], acc[tm][tn]);
    }
    __builtin_amdgcn_s_setprio(0);
  }

  asm volatile("s_nop 7\ns_nop 7");  // asm-MFMA -> VALU read hazard guard

#pragma unroll
  for (int tm = 0; tm < 2; ++tm) {
    l_run[tm] += __shfl_xor(l_run[tm], 16);
    l_run[tm] += __shfl_xor(l_run[tm], 32);
  }

  const int b = bh >> 4, h = bh & 15;
#pragma unroll
  for (int tm = 0; tm < 2; ++tm) {
#pragma unroll
    for (int i = 0; i < 4; ++i) {
      const float lv = __shfl(l_run[tm], (g << 2) + i);
      const float rl = 1.0f / lv;
      const int q = q0 + w * 32 + tm * 16 + (g << 2) + i;
      unsigned short* orow = Ob + ((size_t)b * 2048 + q) * 1024 + h * 64;
#pragma unroll
      for (int tn = 0; tn < 4; ++tn)
        orow[tn * 16 + m] = f2bf(acc[tm][tn][i] * rl);
    }
  }
}

extern "C" void kernel_launch(void* const* d_in, const int* in_sizes, int n_in,
                              void* d_out, int out_size, void* d_ws, size_t ws_size,
                              hipStream_t stream) {
  const float* q = (const float*)d_in[0];
  const float* k = (const float*)d_in[1];
  const float* v = (const float*)d_in[2];
  const int* mask = (const int*)d_in[3];
  const float* wq = (const float*)d_in[4];
  const float* bq = (const float*)d_in[5];
  const float* wk = (const float*)d_in[6];
  const float* bk = (const float*)d_in[7];
  const float* wv = (const float*)d_in[8];
  const float* bv = (const float*)d_in[9];
  const float* wo = (const float*)d_in[10];
  const float* bo = (const float*)d_in[11];

  char* ws = (char*)d_ws;
  unsigned short* Qh = (unsigned short*)ws;                   // A: 16 MB bf16 [B,H,S,D]
  unsigned short* Kh = (unsigned short*)(ws + (16u << 20));   // B: 16 MB bf16 [B,H,S,D]
  unsigned short* VT = (unsigned short*)(ws + (32u << 20));   // C: 16 MB bf16 [B,H,D,S]
  float* Biasf = (float*)(ws + (48u << 20));                  // D: 16 MB f32 [S,S]
  unsigned short* S = (unsigned short*)(ws + (64u << 20));    // E: 16 MB x-bf16, then Ob
  unsigned short* Ob = S;
  // weight slots alias regions dead at their time of use:
  unsigned short* wqb = Kh;                   // dead once gemm-K writes Kh
  unsigned short* wkb = VT;                   // dead once gemm-V writes VT
  unsigned short* wvb = (unsigned short*)Biasf;  // dead once prep_biasf runs
  unsigned short* wob = Qh;                   // written after attn reads Qh
  // total 80 MiB

  const dim3 blk(256);
  // Q projection (pre-scaled by QK_SCALE so softmax is a bare exp2)
  prep_bf16<<<dim3(4096), blk, 0, stream>>>(q, S);
  prep_bf16<<<dim3(512), blk, 0, stream>>>(wq, wqb);
  gemm_bt<0><<<dim3(8, 64), blk, 0, stream>>>(S, wqb, bq, (void*)Qh, 8192, 1024, 1024, QK_SCALE);
  // K projection
  prep_bf16<<<dim3(4096), blk, 0, stream>>>(k, S);
  prep_bf16<<<dim3(512), blk, 0, stream>>>(wk, wkb);
  gemm_bt<0><<<dim3(8, 64), blk, 0, stream>>>(S, wkb, bk, (void*)Kh, 8192, 1024, 1024, 1.0f);
  // V projection swapped: VT = (x@wv^T)^T = wv @ x^T; M=1024, N=8192
  prep_bf16<<<dim3(4096), blk, 0, stream>>>(v, S);
  prep_bf16<<<dim3(512), blk, 0, stream>>>(wv, wvb);
  gemm_bt<1><<<dim3(64, 8), blk, 0, stream>>>(wvb, S, bv, (void*)VT, 1024, 8192, 1024, 1.0f);
  // mask -> f32 additive bias (after V-GEMM so it can overwrite wvb)
  prep_biasf<<<dim3(2048), blk, 0, stream>>>(mask, Biasf);
  // fused attention -> Ob (bf16, [B,S,E]; aliases S)
  attn_fused<<<dim3(1024), blk, 0, stream>>>(Qh, Kh, VT, Biasf, Ob);
  // output projection -> d_out (f32)
  prep_bf16<<<dim3(512), blk, 0, stream>>>(wo, wob);
  gemm_bt<2><<<dim3(8, 64), blk, 0, stream>>>(Ob, wob, bo, d_out, 8192, 1024, 1024, 1.0f);
}